// Round 13
// baseline (596.475 us; speedup 1.0000x reference)
//
#include <hip/hip_runtime.h>
#include <hip/hip_bf16.h>
#include <math.h>
#include <stdint.h>

typedef _Float16 f16;
typedef _Float16 half8 __attribute__((ext_vector_type(8)));
typedef float f32x4 __attribute__((ext_vector_type(4)));

#define B_ 16
#define S_ 4096
#define D_ 1024
#define F_ 1024
#define TOK (B_*S_)
#define TB5 256        // token tile
#define FB5 128        // f tile (per matrix)
#define NFB5 8         // F_/FB5
#define NK5 16         // K-steps of 64
#define NSL 32         // part slices = 8 fb x 4 wavecols
#define NSV 4          // value-pass S chunks
#define CSV (S_/NSV)   // 1024

// async global->LDS, 16B per lane; lds dest = wave-uniform base + lane*16 (HW)
__device__ __forceinline__ void gload_lds16(const void* g, void* l) {
    __builtin_amdgcn_global_load_lds(
        (__attribute__((address_space(1))) const unsigned int*)(unsigned long long)(uintptr_t)g,
        (__attribute__((address_space(3))) unsigned int*)(unsigned int)(uintptr_t)l,
        16, 0, 0);
}

__device__ __forceinline__ void fma2(float2& a, float s, const float2& wv) {
    a.x += s * wv.x; a.y += s * wv.y;
}

// ---------------- kernel 0a: convert x fp32 -> fp16 ----------------
__global__ void cvt_x(const float* __restrict__ x, f16* __restrict__ xh) {
    size_t i = ((size_t)blockIdx.x * 256 + threadIdx.x) * 8;
    float4 a = *(const float4*)(x + i);
    float4 b = *(const float4*)(x + i + 4);
    half8 h = {(f16)a.x,(f16)a.y,(f16)a.z,(f16)a.w,
               (f16)b.x,(f16)b.y,(f16)b.z,(f16)b.w};
    *(half8*)(xh + i) = h;
}

// ------- kernel 0b: pack Wk,Wq -> slice-major MFMA B-fragments (f16) -------
// gw = slice*128 + kt32*4 + mat*2 + nf ; slice = fb*4 + wc (wavecol).
// lane l: f = fb*128 + wc*32 + nf*16 + (l&15), k = kt32*32 + (l>>4)*8 .. +8.
__global__ void cvt_w2(const float* __restrict__ Wk, const float* __restrict__ Wq,
                       f16* __restrict__ wtf) {
    const int gw   = blockIdx.x * 4 + (threadIdx.x >> 6);   // 0..4095
    const int lane = threadIdx.x & 63;
    const int nf = gw & 1, mat = (gw >> 1) & 1, kt32 = (gw >> 2) & 31, slice = gw >> 7;
    const int fb = slice >> 2, wc = slice & 3;
    const float* W = mat ? Wq : Wk;
    const int f  = fb * 128 + wc * 32 + nf * 16 + (lane & 15);
    const int d0 = kt32 * 32 + (lane >> 4) * 8;
    half8 h;
#pragma unroll
    for (int e = 0; e < 8; ++e) h[e] = (f16)W[(size_t)(d0 + e) * F_ + f];
    *(half8*)(wtf + (size_t)gw * 512 + lane * 8) = h;
}

// ------------- kernel 1: fused Q/K GEMM + tanh + diag-dot partials -------------
// m201-geometry port: 256 tok x 128 f x {K,Q}, 8 waves (2 tok-rows x 4 f-cols),
// wave = 128 tok x 32 f x 2 mats (acc 128 regs). BK=64, 4-slot LDS (128 KB),
// stage-ahead-3 via gload_lds (T2 swizzle quad^=row&7 both-sides), W global->reg
// ping-pong. 4 phases/K-step: {4 ds_read || 2 W-loads || 1 stage-issue -> bar ->
// lgkmcnt(0) -> setprio(1) 16 MFMA setprio(0) -> bar}. No manual vmcnt in loop:
// compiler's W(kt-1) reg-dep wait retires stage(kt) one iter before its reads
// (FIFO: stage(kt) issued iter kt-3, W(kt-1) issued iter kt-2, wait at kt-1).
// T1: XCD chunks of 256 origs, fb fastest (8 fb share each X tile in L2).
__launch_bounds__(512, 2)
__global__ void score_gemm(const f16* __restrict__ xh, const f16* __restrict__ wtf,
                           float* __restrict__ part) {
    __shared__ __align__(16) f16 Xs[4][TB5 * 64];   // 4 x 32 KB = 128 KB

    const int hid  = blockIdx.x;                // 2048 blocks
    const int orig = (hid & 7) * 256 + (hid >> 3);
    const int fb   = orig & 7;                  // FAST within XCD chunk
    const int tok0 = (orig >> 3) * TB5;

    const int t = threadIdx.x, lane = t & 63, w = t >> 6;   // w 0..7
    const int wr = (w >> 2) * 128;    // wave token-row offset
    const int wc = w & 3;             // wave f-col (32 f each)

    // --- X staging: chunk c = i*512+t -> row c>>3, quad (t&7)^(row&7) pre-swizzled
    const int srow = t >> 3;                       // 0..63 within row-group
    const int qsrc = (t & 7) ^ (srow & 7);
    const f16* srcX[4];
#pragma unroll
    for (int i = 0; i < 4; ++i)
        srcX[i] = xh + (size_t)(tok0 + i * 64 + srow) * D_ + qsrc * 8;
    // LDS dest (bytes, wave-uniform): slot + i*8192 + w*1024

    // --- A-frag read offsets: byte = row*128 + ((ks*4+(lane>>4))^(lane&7))*16
    int rowb[8];
#pragma unroll
    for (int m = 0; m < 8; ++m)
        rowb[m] = (wr + m * 16 + (lane & 15)) * 128;
    const int kq0 = (((lane >> 4)    ) ^ (lane & 7)) * 16;
    const int kq1 = (((lane >> 4) | 4) ^ (lane & 7)) * 16;

    // --- W fragment base (per-lane): frag(kt32,mat,nf) at (kt32*4+mat*2+nf)*512
    const f16* bW = wtf + (size_t)(fb * 4 + wc) * 128 * 512 + lane * 8;

#define STAGE1(sl, kt, i_)                                                      \
    gload_lds16(srcX[i_] + (size_t)(kt) * 64,                                   \
                (char*)Xs[sl] + (i_) * 8192 + w * 1024)

    f32x4 accK[8][2] = {};
    f32x4 accQ[8][2] = {};
    half8 wf[2][8];

    // prologue: stage tiles 0,1,2 (12 gloads) then W(0) (8 loads)
#pragma unroll
    for (int i = 0; i < 4; ++i) STAGE1(0, 0, i);
#pragma unroll
    for (int i = 0; i < 4; ++i) STAGE1(1, 1, i);
#pragma unroll
    for (int i = 0; i < 4; ++i) STAGE1(2, 2, i);
#pragma unroll
    for (int j = 0; j < 8; ++j)
        wf[0][j] = *(const half8*)(bW + (size_t)((j >> 2) * 4 + (j & 3)) * 512);
    asm volatile("s_waitcnt vmcnt(16)" ::: "memory");   // tile-0's 4 stages retired
    __builtin_amdgcn_s_barrier();

#pragma unroll
    for (int kt = 0; kt < NK5; ++kt) {
        const int cur = kt & 3, par = kt & 1, nx = par ^ 1;
        const char* Xb = (const char*)Xs[cur];
#pragma unroll
        for (int p = 0; p < 4; ++p) {
            const int ks = p >> 1, mh = p & 1;
            // issue W(kt+1) frags 2p,2p+1 (consumed in phase order next iter)
            if (kt < NK5 - 1) {
                wf[nx][2*p]   = *(const half8*)(bW + ((size_t)(2*(kt+1) + (p >> 1)) * 4 + ((2*p)   & 3)) * 512);
                wf[nx][2*p+1] = *(const half8*)(bW + ((size_t)(2*(kt+1) + (p >> 1)) * 4 + ((2*p+1) & 3)) * 512);
            }
            // issue 1 of 4 stage chunks for tile kt+3
            if (kt < NK5 - 3) STAGE1((kt + 3) & 3, kt + 3, p);

            half8 aF[4];
            const int kq = ks ? kq1 : kq0;
#pragma unroll
            for (int i = 0; i < 4; ++i)
                aF[i] = *(const half8*)(Xb + rowb[mh * 4 + i] + kq);

            __builtin_amdgcn_s_barrier();
            asm volatile("s_waitcnt lgkmcnt(0)" ::: "memory");
            __builtin_amdgcn_sched_barrier(0);
            __builtin_amdgcn_s_setprio(1);
#pragma unroll
            for (int i = 0; i < 4; ++i)
#pragma unroll
                for (int n = 0; n < 2; ++n) {
                    accK[mh*4+i][n] = __builtin_amdgcn_mfma_f32_16x16x32_f16(aF[i], wf[par][ks*4 + n],     accK[mh*4+i][n], 0, 0, 0);
                    accQ[mh*4+i][n] = __builtin_amdgcn_mfma_f32_16x16x32_f16(aF[i], wf[par][ks*4 + 2 + n], accQ[mh*4+i][n], 0, 0, 0);
                }
            __builtin_amdgcn_s_setprio(0);
            __builtin_amdgcn_s_barrier();
        }
    }
#undef STAGE1

    // epilogue: fully wave-local. tanh-product, reduce over f (n + lane&15),
    // write own 128 tokens into slice fb*4+wc.
    const int slice = fb * 4 + wc;
#pragma unroll
    for (int m = 0; m < 8; ++m) {
        float s[4] = {0.f, 0.f, 0.f, 0.f};
#pragma unroll
        for (int n = 0; n < 2; ++n)
#pragma unroll
            for (int j = 0; j < 4; ++j)
                s[j] += tanhf(accQ[m][n][j]) * tanhf(accK[m][n][j]);
#pragma unroll
        for (int j = 0; j < 4; ++j) {
            s[j] += __shfl_xor(s[j], 1);
            s[j] += __shfl_xor(s[j], 2);
            s[j] += __shfl_xor(s[j], 4);
            s[j] += __shfl_xor(s[j], 8);
        }
        if ((lane & 15) == 0) {
            int g = lane >> 4;
#pragma unroll
            for (int j = 0; j < 4; ++j)
                part[(size_t)slice * TOK + tok0 + wr + m * 16 + g * 4 + j] = s[j];
        }
    }
}

// ------------- kernel 2a: reduce slice partials -> scores[tok] -------------
__global__ void sum_k(const float* __restrict__ part, float* __restrict__ scores) {
    int i = blockIdx.x * 256 + threadIdx.x;
    float s = 0.f;
#pragma unroll
    for (int sl = 0; sl < NSL; ++sl) s += part[(size_t)sl * TOK + i];
    scores[i] = s;
}

// ------------- kernel 2b: per-batch softmax over S -------------
__global__ void softmax_k(const float* __restrict__ scores, float* __restrict__ out) {
    __shared__ float sc[S_];
    __shared__ float red[256];
    const int b = blockIdx.x, t = threadIdx.x;
    float lmax = -1e30f;
    for (int i = t; i < S_; i += 256) {
        float s = scores[(size_t)b * S_ + i];
        sc[i] = s;
        lmax = fmaxf(lmax, s);
    }
    red[t] = lmax; __syncthreads();
    for (int o = 128; o > 0; o >>= 1) { if (t < o) red[t] = fmaxf(red[t], red[t + o]); __syncthreads(); }
    const float mx = red[0]; __syncthreads();
    float lsum = 0.f;
    for (int i = t; i < S_; i += 256) { float e = expf(sc[i] - mx); sc[i] = e; lsum += e; }
    red[t] = lsum; __syncthreads();
    for (int o = 128; o > 0; o >>= 1) { if (t < o) red[t] += red[t + o]; __syncthreads(); }
    const float inv = 1.0f / red[0];
    for (int i = t; i < S_; i += 256)
        out[(size_t)B_ * F_ + (size_t)b * S_ + i] = sc[i] * inv;
}

// --- kernel 3: sparse value pass, 512 threads, thread owns 2 f-cols (float2) ---
__launch_bounds__(512)
__global__ void value_k5(const float* __restrict__ x, const float* __restrict__ Wv,
                         const float* __restrict__ p_in, float* __restrict__ vpart) {
    __shared__ __align__(16) float xs[8][D_];   // 32 KB
    __shared__ float ps[CSV];
    __shared__ int   idxs[CSV];
    __shared__ int   wsum[8];
    __shared__ int   rbase_s;
    const int b = blockIdx.x, c = blockIdx.y;
    const int t = threadIdx.x, lane = t & 63, w = t >> 6;
    const int s0 = c * CSV;

    if (t == 0) rbase_s = 0;
    __syncthreads();
#pragma unroll 1
    for (int r = 0; r < 2; ++r) {
        int i = r * 512 + t;
        float p = p_in[(size_t)b * S_ + s0 + i];
        bool flag = p > 1e-7f;
        unsigned long long mask = __ballot(flag);
        if (lane == 0) wsum[w] = __popcll(mask);
        __syncthreads();
        int base = rbase_s;
#pragma unroll
        for (int k = 0; k < 8; ++k) if (k < w) base += wsum[k];
        if (flag) {
            int pos = base + __popcll(mask & ((1ull << lane) - 1ull));
            idxs[pos] = s0 + i;
            ps[pos] = p;
        }
        __syncthreads();
        if (t == 0) {
            int sum = 0;
#pragma unroll
            for (int k = 0; k < 8; ++k) sum += wsum[k];
            rbase_s += sum;
        }
        __syncthreads();
    }
    const int cnt = rbase_s;

    float2 acc = {0.f, 0.f};
    for (int g = 0; g < cnt; g += 8) {
        __syncthreads();
        const int ng = cnt - g;
#pragma unroll
        for (int r = 0; r < 8; ++r) {
            float2 v = {0.f, 0.f};
            if (r < ng)
                v = ((const float2*)(x + ((size_t)b * S_ + idxs[g + r]) * D_))[t];
            ((float2*)xs[r])[t] = v;
        }
        __syncthreads();
        if (ng >= 5) {
            float2 a[8] = {};
#pragma unroll 2
            for (int dq = 0; dq < D_ / 4; ++dq) {
                const float* wrp = Wv + (size_t)dq * 4 * F_ + 2 * t;
                float2 wv0 = *(const float2*)(wrp         );
                float2 wv1 = *(const float2*)(wrp + F_    );
                float2 wv2 = *(const float2*)(wrp + 2 * F_);
                float2 wv3 = *(const float2*)(wrp + 3 * F_);
#pragma unroll
                for (int r = 0; r < 8; ++r) {
                    float4 xr = ((const float4*)xs[r])[dq];
                    fma2(a[r], xr.x, wv0); fma2(a[r], xr.y, wv1);
                    fma2(a[r], xr.z, wv2); fma2(a[r], xr.w, wv3);
                }
            }
#pragma unroll
            for (int r = 0; r < 8; ++r)
                if (g + r < cnt) {
                    float pw = ps[g + r];
                    acc.x += pw * tanhf(a[r].x);
                    acc.y += pw * tanhf(a[r].y);
                }
        } else {
            float2 a[4] = {};
#pragma unroll 2
            for (int dq = 0; dq < D_ / 4; ++dq) {
                const float* wrp = Wv + (size_t)dq * 4 * F_ + 2 * t;
                float2 wv0 = *(const float2*)(wrp         );
                float2 wv1 = *(const float2*)(wrp + F_    );
                float2 wv2 = *(const float2*)(wrp + 2 * F_);
                float2 wv3 = *(const float2*)(wrp + 3 * F_);
#pragma unroll
                for (int r = 0; r < 4; ++r) {
                    float4 xr = ((const float4*)xs[r])[dq];
                    fma2(a[r], xr.x, wv0); fma2(a[r], xr.y, wv1);
                    fma2(a[r], xr.z, wv2); fma2(a[r], xr.w, wv3);
                }
            }
#pragma unroll
            for (int r = 0; r < 4; ++r)
                if (g + r < cnt) {
                    float pw = ps[g + r];
                    acc.x += pw * tanhf(a[r].x);
                    acc.y += pw * tanhf(a[r].y);
                }
        }
    }
    ((float2*)(vpart + ((size_t)c * B_ + b) * F_))[t] = acc;
}

// ------------- kernel 4: reduce chunk partials -------------
__global__ void value_red(const float* __restrict__ vpart, float* __restrict__ out) {
    int i = blockIdx.x * 256 + threadIdx.x;
    float s = 0.f;
#pragma unroll
    for (int c = 0; c < NSV; ++c) s += vpart[(size_t)c * B_ * F_ + i];
    out[i] = s;
}

extern "C" void kernel_launch(void* const* d_in, const int* in_sizes, int n_in,
                              void* d_out, int out_size, void* d_ws, size_t ws_size,
                              hipStream_t stream) {
    const float* x  = (const float*)d_in[0];
    const float* Wk = (const float*)d_in[1];
    const float* Wq = (const float*)d_in[2];
    const float* Wv = (const float*)d_in[3];
    float* out = (float*)d_out;
    char* ws = (char*)d_ws;

    f16*   xh     = (f16*)ws;                                            // 128 MB
    f16*   wtf    = (f16*)(ws + (size_t)TOK * D_ * 2);                   // 4 MB slice-major W
    float* part   = (float*)(ws + (size_t)TOK * D_ * 2 + 2 * (size_t)D_ * F_ * 2); // 8 MB
    float* scores = part + (size_t)NSL * TOK;                            // 256 KB

    cvt_x<<<TOK * D_ / 8 / 256, 256, 0, stream>>>(x, xh);
    cvt_w2<<<1024, 256, 0, stream>>>(Wk, Wq, wtf);
    score_gemm<<<NFB5 * (TOK / TB5), 512, 0, stream>>>(xh, wtf, part);
    sum_k<<<TOK / 256, 256, 0, stream>>>(part, scores);
    softmax_k<<<B_, 256, 0, stream>>>(scores, out);
    float* vpart = part;
    const float* p_in = out + (size_t)B_ * F_;
    value_k5<<<dim3(B_, NSV), 512, 0, stream>>>(x, Wv, p_in, vpart);
    value_red<<<B_ * F_ / 256, 256, 0, stream>>>(vpart, out);
}

// Round 14
// 587.687 us; speedup vs baseline: 1.0150x; 1.0150x over previous
//
#include <hip/hip_runtime.h>
#include <hip/hip_bf16.h>
#include <math.h>
#include <stdint.h>

typedef _Float16 f16;
typedef _Float16 half8 __attribute__((ext_vector_type(8)));
typedef float f32x4 __attribute__((ext_vector_type(4)));

#define B_ 16
#define S_ 4096
#define D_ 1024
#define F_ 1024
#define TOK (B_*S_)
#define TB3 128        // token tile
#define FB3 64         // f tile
#define NFB3 16        // F_/FB3
#define NT3 32         // D_/32 K-tiles
#define NSV 4          // value-pass S chunks
#define CSV (S_/NSV)   // 1024

__device__ __forceinline__ void fma2(float2& a, float s, const float2& wv) {
    a.x += s * wv.x; a.y += s * wv.y;
}

// ------- kernel 0: pack Wk,Wq (fp32 [D][F]) -> MFMA-fragment-major f16 -------
// frag gw = ((mat*16+fb)*32 + kt)*4 + nblk ; lane l holds f = fb*64+nblk*16+(l&15),
// k = kt*32+(l>>4)*8..+8 (B-operand of mfma_f32_16x16x32_f16), contiguous per wave.
__global__ void cvt_w2(const float* __restrict__ Wk, const float* __restrict__ Wq,
                       f16* __restrict__ wtf) {
    const int gw   = blockIdx.x * 4 + (threadIdx.x >> 6);   // 0..4095
    const int lane = threadIdx.x & 63;
    const int nblk = gw & 3, kt = (gw >> 2) & 31, fb = (gw >> 7) & 15, mat = gw >> 11;
    const float* W = mat ? Wq : Wk;
    const int f  = fb * 64 + nblk * 16 + (lane & 15);
    const int d0 = kt * 32 + (lane >> 4) * 8;
    half8 h;
#pragma unroll
    for (int e = 0; e < 8; ++e) h[e] = (f16)W[(size_t)(d0 + e) * F_ + f];
    *(half8*)(wtf + (size_t)gw * 512 + lane * 8) = h;
}

// ------------- kernel 1: FUSED cvt + Q/K GEMM + tanh + diag-dot partials -------------
// R12-proven geometry (339us): 128x64 tile, 4 waves, 64tok x 32f x 2 mats/wave,
// BK=32, 4 LDS slots, one s_barrier/tile, W frag-major global->reg ping-pong,
// T1 fb-fastest XCD chunks. NEW: X read DIRECTLY as fp32 from x (no cvt_x pass,
// no xh buffer): reg-staged distance-2 prefetch, fp32->f16 convert in VALU,
// swizzled ds_write (T2 involution on write side; read side unchanged).
__launch_bounds__(256, 3)
__global__ void score_gemm(const float* __restrict__ x, const f16* __restrict__ wtf,
                           float* __restrict__ part) {
    __shared__ __align__(16) f16 Xs[4][TB3 * 32];   // 4 x 8 KB
    __shared__ float sred[2][TB3];                  // 1 KB

    const int hid  = blockIdx.x;
    const int orig = (hid & 7) * 1024 + (hid >> 3);
    const int fb   = orig & 15;                 // FAST: 16 fb per X tile
    const int tok0 = (orig >> 4) * TB3;

    const int t = threadIdx.x, lane = t & 63, w = t >> 6;
    const int wr = (w >> 1) * 64;     // token offset of wave sub-tile
    const int wc = (w & 1) * 32;      // f offset of wave sub-tile

    // fused X staging: thread t -> row r = t>>1, half h = t&1 (16 f16 elems)
    const int r = t >> 1, h = t & 1;
    const float* gx = x + (size_t)(tok0 + r) * D_ + h * 16;
    const int qs0 = (h * 2)     ^ ((r >> 1) & 3);   // T2 involution, write side
    const int qs1 = (h * 2 + 1) ^ ((r >> 1) & 3);
    const int wb0 = r * 64 + qs0 * 16;              // byte offsets within slot
    const int wb1 = r * 64 + qs1 * 16;

    // A-fragment read offsets (swizzled read side, unchanged from R12)
    int offA[4];
#pragma unroll
    for (int m = 0; m < 4; ++m) {
        int row = wr + m * 16 + (lane & 15);
        int q   = (lane >> 4) ^ ((row >> 1) & 3);
        offA[m] = row * 32 + q * 8;
    }

    // W fragment base pointers (per-lane): frag elem off = ((fb*32+kt)*4+nblk)*512
    const f16* bK = wtf + (((size_t)fb * NT3 * 4) + 2 * (w & 1)) * 512 + lane * 8;
    const f16* bQ = bK + (size_t)NFB3 * NT3 * 4 * 512;   // mat=1 half

#define LOADX(buf, kt) do {                                           \
        const float4* s_ = (const float4*)(gx + (size_t)(kt) * 32);   \
        buf[0] = s_[0]; buf[1] = s_[1]; buf[2] = s_[2]; buf[3] = s_[3];\
    } while (0)
#define WRITEX(sl, buf) do {                                                        \
        half8 lo_ = {(f16)buf[0].x,(f16)buf[0].y,(f16)buf[0].z,(f16)buf[0].w,       \
                     (f16)buf[1].x,(f16)buf[1].y,(f16)buf[1].z,(f16)buf[1].w};      \
        half8 hi_ = {(f16)buf[2].x,(f16)buf[2].y,(f16)buf[2].z,(f16)buf[2].w,       \
                     (f16)buf[3].x,(f16)buf[3].y,(f16)buf[3].z,(f16)buf[3].w};      \
        *(half8*)((char*)Xs[sl] + wb0) = lo_;                                       \
        *(half8*)((char*)Xs[sl] + wb1) = hi_;                                       \
    } while (0)

    f32x4 accK[4][2] = {};
    f32x4 accQ[4][2] = {};
    half8 wKf[2][2], wQf[2][2];
    float4 xrA[4], xrB[4];

    // prologue: tiles 0,1 -> LDS; tiles 2,3 -> regs; W(0) -> regs
    LOADX(xrA, 0);
    LOADX(xrB, 1);
#pragma unroll
    for (int n = 0; n < 2; ++n) {
        wKf[0][n] = *(const half8*)(bK + n * 512);
        wQf[0][n] = *(const half8*)(bQ + n * 512);
    }
    WRITEX(0, xrA);
    LOADX(xrA, 2);
    WRITEX(1, xrB);
    LOADX(xrB, 3);
    __syncthreads();    // drains lgkm+vm, full barrier (prologue only)

#pragma unroll
    for (int kt = 0; kt < NT3; ++kt) {
        const int cur = kt & 3, par = kt & 1, nx = par ^ 1;

        // 1. write tile kt+2 to slot (kt+2)&3 (WAR-safe: last read 2 barriers ago)
        if (kt < NT3 - 2) {
            if ((kt & 1) == 0) WRITEX((kt + 2) & 3, xrA);
            else               WRITEX((kt + 2) & 3, xrB);
        }
        // 2. refill the just-consumed reg buffer with tile kt+4
        if (kt < NT3 - 4) {
            if ((kt & 1) == 0) LOADX(xrA, kt + 4);
            else               LOADX(xrB, kt + 4);
        }
        // 3. W(kt+1) frag loads (reg ping-pong)
        if (kt < NT3 - 1) {
#pragma unroll
            for (int n = 0; n < 2; ++n) {
                wKf[nx][n] = *(const half8*)(bK + ((size_t)(kt + 1) * 4 + n) * 512);
                wQf[nx][n] = *(const half8*)(bQ + ((size_t)(kt + 1) * 4 + n) * 512);
            }
        }

        // 4. fragments + MFMA (compiler lgkm waits for aF also retire older ds_writes)
        half8 aF[4];
#pragma unroll
        for (int m = 0; m < 4; ++m) aF[m] = *(const half8*)(Xs[cur] + offA[m]);
#pragma unroll
        for (int n = 0; n < 2; ++n)
#pragma unroll
            for (int m = 0; m < 4; ++m) {
                accK[m][n] = __builtin_amdgcn_mfma_f32_16x16x32_f16(aF[m], wKf[par][n], accK[m][n], 0, 0, 0);
                accQ[m][n] = __builtin_amdgcn_mfma_f32_16x16x32_f16(aF[m], wQf[par][n], accQ[m][n], 0, 0, 0);
            }
        if (kt < NT3 - 1) __builtin_amdgcn_s_barrier();
    }
#undef LOADX
#undef WRITEX

    // epilogue: tanh, product, reduce over f, combine 2 f-wave-cols
#pragma unroll
    for (int m = 0; m < 4; ++m) {
        float s[4] = {0.f, 0.f, 0.f, 0.f};
#pragma unroll
        for (int n = 0; n < 2; ++n)
#pragma unroll
            for (int j = 0; j < 4; ++j)
                s[j] += tanhf(accQ[m][n][j]) * tanhf(accK[m][n][j]);
#pragma unroll
        for (int j = 0; j < 4; ++j) {
            s[j] += __shfl_xor(s[j], 1);
            s[j] += __shfl_xor(s[j], 2);
            s[j] += __shfl_xor(s[j], 4);
            s[j] += __shfl_xor(s[j], 8);
        }
        if ((lane & 15) == 0) {
            int g = lane >> 4;
#pragma unroll
            for (int j = 0; j < 4; ++j)
                sred[w & 1][wr + m * 16 + g * 4 + j] = s[j];
        }
    }
    __syncthreads();
    if (t < TB3)
        part[(size_t)fb * TOK + tok0 + t] = sred[0][t] + sred[1][t];
}

// ------------- kernel 2a: reduce fb partials -> scores[tok] -------------
__global__ void sum_k(const float* __restrict__ part, float* __restrict__ scores) {
    int i = blockIdx.x * 256 + threadIdx.x;
    float s = 0.f;
#pragma unroll
    for (int fb = 0; fb < NFB3; ++fb) s += part[(size_t)fb * TOK + i];
    scores[i] = s;
}

// ------------- kernel 2b: per-batch softmax over S -------------
__global__ void softmax_k(const float* __restrict__ scores, float* __restrict__ out) {
    __shared__ float sc[S_];
    __shared__ float red[256];
    const int b = blockIdx.x, t = threadIdx.x;
    float lmax = -1e30f;
    for (int i = t; i < S_; i += 256) {
        float s = scores[(size_t)b * S_ + i];
        sc[i] = s;
        lmax = fmaxf(lmax, s);
    }
    red[t] = lmax; __syncthreads();
    for (int o = 128; o > 0; o >>= 1) { if (t < o) red[t] = fmaxf(red[t], red[t + o]); __syncthreads(); }
    const float mx = red[0]; __syncthreads();
    float lsum = 0.f;
    for (int i = t; i < S_; i += 256) { float e = expf(sc[i] - mx); sc[i] = e; lsum += e; }
    red[t] = lsum; __syncthreads();
    for (int o = 128; o > 0; o >>= 1) { if (t < o) red[t] += red[t + o]; __syncthreads(); }
    const float inv = 1.0f / red[0];
    for (int i = t; i < S_; i += 256)
        out[(size_t)B_ * F_ + (size_t)b * S_ + i] = sc[i] * inv;
}

// --- kernel 3: sparse value pass, 512 threads, thread owns 2 f-cols (float2) ---
__launch_bounds__(512)
__global__ void value_k5(const float* __restrict__ x, const float* __restrict__ Wv,
                         const float* __restrict__ p_in, float* __restrict__ vpart) {
    __shared__ __align__(16) float xs[8][D_];   // 32 KB
    __shared__ float ps[CSV];
    __shared__ int   idxs[CSV];
    __shared__ int   wsum[8];
    __shared__ int   rbase_s;
    const int b = blockIdx.x, c = blockIdx.y;
    const int t = threadIdx.x, lane = t & 63, w = t >> 6;
    const int s0 = c * CSV;

    if (t == 0) rbase_s = 0;
    __syncthreads();
#pragma unroll 1
    for (int r = 0; r < 2; ++r) {
        int i = r * 512 + t;
        float p = p_in[(size_t)b * S_ + s0 + i];
        bool flag = p > 1e-7f;
        unsigned long long mask = __ballot(flag);
        if (lane == 0) wsum[w] = __popcll(mask);
        __syncthreads();
        int base = rbase_s;
#pragma unroll
        for (int k = 0; k < 8; ++k) if (k < w) base += wsum[k];
        if (flag) {
            int pos = base + __popcll(mask & ((1ull << lane) - 1ull));
            idxs[pos] = s0 + i;
            ps[pos] = p;
        }
        __syncthreads();
        if (t == 0) {
            int sum = 0;
#pragma unroll
            for (int k = 0; k < 8; ++k) sum += wsum[k];
            rbase_s += sum;
        }
        __syncthreads();
    }
    const int cnt = rbase_s;

    float2 acc = {0.f, 0.f};
    for (int g = 0; g < cnt; g += 8) {
        __syncthreads();
        const int ng = cnt - g;
#pragma unroll
        for (int r = 0; r < 8; ++r) {
            float2 v = {0.f, 0.f};
            if (r < ng)
                v = ((const float2*)(x + ((size_t)b * S_ + idxs[g + r]) * D_))[t];
            ((float2*)xs[r])[t] = v;
        }
        __syncthreads();
        if (ng >= 5) {
            float2 a[8] = {};
#pragma unroll 2
            for (int dq = 0; dq < D_ / 4; ++dq) {
                const float* wrp = Wv + (size_t)dq * 4 * F_ + 2 * t;
                float2 wv0 = *(const float2*)(wrp         );
                float2 wv1 = *(const float2*)(wrp + F_    );
                float2 wv2 = *(const float2*)(wrp + 2 * F_);
                float2 wv3 = *(const float2*)(wrp + 3 * F_);
#pragma unroll
                for (int r = 0; r < 8; ++r) {
                    float4 xr = ((const float4*)xs[r])[dq];
                    fma2(a[r], xr.x, wv0); fma2(a[r], xr.y, wv1);
                    fma2(a[r], xr.z, wv2); fma2(a[r], xr.w, wv3);
                }
            }
#pragma unroll
            for (int r = 0; r < 8; ++r)
                if (g + r < cnt) {
                    float pw = ps[g + r];
                    acc.x += pw * tanhf(a[r].x);
                    acc.y += pw * tanhf(a[r].y);
                }
        } else {
            float2 a[4] = {};
#pragma unroll 2
            for (int dq = 0; dq < D_ / 4; ++dq) {
                const float* wrp = Wv + (size_t)dq * 4 * F_ + 2 * t;
                float2 wv0 = *(const float2*)(wrp         );
                float2 wv1 = *(const float2*)(wrp + F_    );
                float2 wv2 = *(const float2*)(wrp + 2 * F_);
                float2 wv3 = *(const float2*)(wrp + 3 * F_);
#pragma unroll
                for (int r = 0; r < 4; ++r) {
                    float4 xr = ((const float4*)xs[r])[dq];
                    fma2(a[r], xr.x, wv0); fma2(a[r], xr.y, wv1);
                    fma2(a[r], xr.z, wv2); fma2(a[r], xr.w, wv3);
                }
            }
#pragma unroll
            for (int r = 0; r < 4; ++r)
                if (g + r < cnt) {
                    float pw = ps[g + r];
                    acc.x += pw * tanhf(a[r].x);
                    acc.y += pw * tanhf(a[r].y);
                }
        }
    }
    ((float2*)(vpart + ((size_t)c * B_ + b) * F_))[t] = acc;
}

// ------------- kernel 4: reduce chunk partials -------------
__global__ void value_red(const float* __restrict__ vpart, float* __restrict__ out) {
    int i = blockIdx.x * 256 + threadIdx.x;
    float s = 0.f;
#pragma unroll
    for (int c = 0; c < NSV; ++c) s += vpart[(size_t)c * B_ * F_ + i];
    out[i] = s;
}

extern "C" void kernel_launch(void* const* d_in, const int* in_sizes, int n_in,
                              void* d_out, int out_size, void* d_ws, size_t ws_size,
                              hipStream_t stream) {
    const float* x  = (const float*)d_in[0];
    const float* Wk = (const float*)d_in[1];
    const float* Wq = (const float*)d_in[2];
    const float* Wv = (const float*)d_in[3];
    float* out = (float*)d_out;
    char* ws = (char*)d_ws;

    f16*   wtf    = (f16*)ws;                                  // 4 MB frag-major W
    float* part   = (float*)(ws + 2 * (size_t)D_ * F_ * 2);    // 4 MB (16 fb slices)
    float* scores = part + (size_t)NFB3 * TOK;                 // 256 KB

    cvt_w2<<<1024, 256, 0, stream>>>(Wk, Wq, wtf);
    score_gemm<<<NFB3 * (TOK / TB3), 256, 0, stream>>>(x, wtf, part);
    sum_k<<<TOK / 256, 256, 0, stream>>>(part, scores);
    softmax_k<<<B_, 256, 0, stream>>>(scores, out);
    float* vpart = part;
    const float* p_in = out + (size_t)B_ * F_;
    value_k5<<<dim3(B_, NSV), 512, 0, stream>>>(x, Wv, p_in, vpart);
    value_red<<<B_ * F_ / 256, 256, 0, stream>>>(vpart, out);
}

// Round 16
// 552.981 us; speedup vs baseline: 1.0787x; 1.0628x over previous
//
#include <hip/hip_runtime.h>
#include <hip/hip_bf16.h>
#include <math.h>
#include <stdint.h>

typedef _Float16 f16;
typedef _Float16 half8 __attribute__((ext_vector_type(8)));
typedef float f32x4 __attribute__((ext_vector_type(4)));

#define B_ 16
#define S_ 4096
#define D_ 1024
#define F_ 1024
#define TOK (B_*S_)
#define TB3 128        // token tile
#define FB3 64         // f tile
#define NFB3 16        // F_/FB3
#define NT3 32         // D_/32 K-tiles
#define NSV 4          // value-pass S chunks
#define CSV (S_/NSV)   // 1024

// async global->LDS, 16B per lane; lds dest = wave-uniform base + lane*16 (HW)
__device__ __forceinline__ void gload_lds16(const void* g, void* l) {
    __builtin_amdgcn_global_load_lds(
        (__attribute__((address_space(1))) const unsigned int*)(unsigned long long)(uintptr_t)g,
        (__attribute__((address_space(3))) unsigned int*)(unsigned int)(uintptr_t)l,
        16, 0, 0);
}

__device__ __forceinline__ void fma2(float2& a, float s, const float2& wv) {
    a.x += s * wv.x; a.y += s * wv.y;
}

// ---------------- kernel 0a: convert x fp32 -> fp16 ----------------
__global__ void cvt_x(const float* __restrict__ x, f16* __restrict__ xh) {
    size_t i = ((size_t)blockIdx.x * 256 + threadIdx.x) * 8;
    float4 a = *(const float4*)(x + i);
    float4 b = *(const float4*)(x + i + 4);
    half8 h = {(f16)a.x,(f16)a.y,(f16)a.z,(f16)a.w,
               (f16)b.x,(f16)b.y,(f16)b.z,(f16)b.w};
    *(half8*)(xh + i) = h;
}

// ------- kernel 0b: pack Wk,Wq (fp32 [D][F]) -> MFMA-fragment-major f16 -------
// frag gw = ((mat*16+fb)*32 + kt)*4 + nblk ; lane l holds f = fb*64+nblk*16+(l&15),
// k = kt*32+(l>>4)*8..+8 (B-operand of mfma_f32_16x16x32_f16), contiguous per wave.
__global__ void cvt_w2(const float* __restrict__ Wk, const float* __restrict__ Wq,
                       f16* __restrict__ wtf) {
    const int gw   = blockIdx.x * 4 + (threadIdx.x >> 6);   // 0..4095
    const int lane = threadIdx.x & 63;
    const int nblk = gw & 3, kt = (gw >> 2) & 31, fb = (gw >> 7) & 15, mat = gw >> 11;
    const float* W = mat ? Wq : Wk;
    const int f  = fb * 64 + nblk * 16 + (lane & 15);
    const int d0 = kt * 32 + (lane >> 4) * 8;
    half8 h;
#pragma unroll
    for (int e = 0; e < 8; ++e) h[e] = (f16)W[(size_t)(d0 + e) * F_ + f];
    *(half8*)(wtf + (size_t)gw * 512 + lane * 8) = h;
}

// ------------- kernel 1: fused Q/K GEMM + tanh + diag-dot partials -------------
// R12-exact proven config (339us): 128x64 tile, 4 waves, 64tok x 32f x 2 mats,
// BK=32, 4 LDS slots, one s_barrier/tile, X gload_lds + T2 swizzle both-sides,
// W frag-major global->reg ping-pong (compiler-counted waits), T1 fb-fastest.
__launch_bounds__(256, 4)
__global__ void score_gemm(const f16* __restrict__ xh, const f16* __restrict__ wtf,
                           float* __restrict__ part) {
    __shared__ __align__(16) f16 Xs[4][TB3 * 32];   // 4 x 8 KB
    __shared__ float sred[2][TB3];                  // 1 KB

    const int hid  = blockIdx.x;
    const int orig = (hid & 7) * 1024 + (hid >> 3);
    const int fb   = orig & 15;                 // FAST: 16 fb per X tile
    const int tok0 = (orig >> 4) * TB3;

    const int t = threadIdx.x, lane = t & 63, w = t >> 6;
    const int wr = (w >> 1) * 64;     // token offset of wave sub-tile
    const int wc = (w & 1) * 32;      // f offset of wave sub-tile

    // X staging sources, pre-swizzled quad (involution q ^ ((row>>1)&3))
    const int rx0 = t >> 2,         qx0 = (t & 3) ^ ((rx0 >> 1) & 3);
    const int rx1 = (t + 256) >> 2, qx1 = (t & 3) ^ ((rx1 >> 1) & 3);
    const f16* srcX0 = xh + (size_t)(tok0 + rx0) * D_ + qx0 * 8;
    const f16* srcX1 = xh + (size_t)(tok0 + rx1) * D_ + qx1 * 8;
    const int wbase = w * 1024;       // wave-uniform LDS byte base

    // A-fragment read offsets (swizzled read side)
    int offA[4];
#pragma unroll
    for (int m = 0; m < 4; ++m) {
        int row = wr + m * 16 + (lane & 15);
        int q   = (lane >> 4) ^ ((row >> 1) & 3);
        offA[m] = row * 32 + q * 8;
    }

    // W fragment base pointers (per-lane): frag elem off = ((fb*32+kt)*4+nblk)*512
    const f16* bK = wtf + (((size_t)fb * NT3 * 4) + 2 * (w & 1)) * 512 + lane * 8;
    const f16* bQ = bK + (size_t)NFB3 * NT3 * 4 * 512;   // mat=1 half

#define STAGE_X(sl, kof) do {                                         \
        gload_lds16(srcX0 + (kof), (char*)Xs[sl] + wbase);            \
        gload_lds16(srcX1 + (kof), (char*)Xs[sl] + 4096 + wbase);     \
    } while (0)

    f32x4 accK[4][2] = {};
    f32x4 accQ[4][2] = {};
    half8 wKf[2][2], wQf[2][2];

    // prologue: X0,X1,X2 staged, then W(0) frags; vmcnt(8) forces X0;
    // MFMA(0)'s auto-wait on W(0) (newest) drains X1,X2 for iters 1,2.
    STAGE_X(0, 0);
    STAGE_X(1, 32);
    STAGE_X(2, 64);
#pragma unroll
    for (int n = 0; n < 2; ++n) {
        wKf[0][n] = *(const half8*)(bK + n * 512);
        wQf[0][n] = *(const half8*)(bQ + n * 512);
    }
    asm volatile("s_waitcnt vmcnt(8)" ::: "memory");
    __builtin_amdgcn_s_barrier();

#pragma unroll
    for (int kt = 0; kt < NT3; ++kt) {
        const int cur = kt & 3, par = kt & 1, nx = par ^ 1;
        if (kt < NT3 - 1) {
#pragma unroll
            for (int n = 0; n < 2; ++n) {
                wKf[nx][n] = *(const half8*)(bK + ((size_t)(kt + 1) * 4 + n) * 512);
                wQf[nx][n] = *(const half8*)(bQ + ((size_t)(kt + 1) * 4 + n) * 512);
            }
        }
        if (kt < NT3 - 3) STAGE_X((kt + 3) & 3, (kt + 3) * 32);

        half8 aF[4];
#pragma unroll
        for (int m = 0; m < 4; ++m) aF[m] = *(const half8*)(Xs[cur] + offA[m]);
#pragma unroll
        for (int n = 0; n < 2; ++n)
#pragma unroll
            for (int m = 0; m < 4; ++m) {
                accK[m][n] = __builtin_amdgcn_mfma_f32_16x16x32_f16(aF[m], wKf[par][n], accK[m][n], 0, 0, 0);
                accQ[m][n] = __builtin_amdgcn_mfma_f32_16x16x32_f16(aF[m], wQf[par][n], accQ[m][n], 0, 0, 0);
            }
        if (kt < NT3 - 1) __builtin_amdgcn_s_barrier();
    }
#undef STAGE_X

    // epilogue: tanh, product, reduce over f, combine 2 f-wave-cols
#pragma unroll
    for (int m = 0; m < 4; ++m) {
        float s[4] = {0.f, 0.f, 0.f, 0.f};
#pragma unroll
        for (int n = 0; n < 2; ++n)
#pragma unroll
            for (int j = 0; j < 4; ++j)
                s[j] += tanhf(accQ[m][n][j]) * tanhf(accK[m][n][j]);
#pragma unroll
        for (int j = 0; j < 4; ++j) {
            s[j] += __shfl_xor(s[j], 1);
            s[j] += __shfl_xor(s[j], 2);
            s[j] += __shfl_xor(s[j], 4);
            s[j] += __shfl_xor(s[j], 8);
        }
        if ((lane & 15) == 0) {
            int g = lane >> 4;
#pragma unroll
            for (int j = 0; j < 4; ++j)
                sred[w & 1][wr + m * 16 + g * 4 + j] = s[j];
        }
    }
    __syncthreads();
    if (t < TB3)
        part[(size_t)fb * TOK + tok0 + t] = sred[0][t] + sred[1][t];
}

// ---- kernel 2: per-batch softmax over S (fb-sum fused, same order as sum_k) ----
__global__ void softmax_k(const float* __restrict__ part, float* __restrict__ out) {
    __shared__ float sc[S_];
    __shared__ float red[256];
    const int b = blockIdx.x, t = threadIdx.x;
    float lmax = -1e30f;
    for (int i = t; i < S_; i += 256) {
        float s = 0.f;
#pragma unroll
        for (int fb = 0; fb < NFB3; ++fb) s += part[(size_t)fb * TOK + b * S_ + i];
        sc[i] = s;
        lmax = fmaxf(lmax, s);
    }
    red[t] = lmax; __syncthreads();
    for (int o = 128; o > 0; o >>= 1) { if (t < o) red[t] = fmaxf(red[t], red[t + o]); __syncthreads(); }
    const float mx = red[0]; __syncthreads();
    float lsum = 0.f;
    for (int i = t; i < S_; i += 256) { float e = expf(sc[i] - mx); sc[i] = e; lsum += e; }
    red[t] = lsum; __syncthreads();
    for (int o = 128; o > 0; o >>= 1) { if (t < o) red[t] += red[t + o]; __syncthreads(); }
    const float inv = 1.0f / red[0];
    for (int i = t; i < S_; i += 256)
        out[(size_t)B_ * F_ + (size_t)b * S_ + i] = sc[i] * inv;
}

// --- kernel 3: sparse value pass, 512 threads, thread owns 2 f-cols (float2) ---
__launch_bounds__(512)
__global__ void value_k5(const float* __restrict__ x, const float* __restrict__ Wv,
                         const float* __restrict__ p_in, float* __restrict__ vpart) {
    __shared__ __align__(16) float xs[8][D_];   // 32 KB
    __shared__ float ps[CSV];
    __shared__ int   idxs[CSV];
    __shared__ int   wsum[8];
    __shared__ int   rbase_s;
    const int b = blockIdx.x, c = blockIdx.y;
    const int t = threadIdx.x, lane = t & 63, w = t >> 6;
    const int s0 = c * CSV;

    if (t == 0) rbase_s = 0;
    __syncthreads();
#pragma unroll 1
    for (int r = 0; r < 2; ++r) {
        int i = r * 512 + t;
        float p = p_in[(size_t)b * S_ + s0 + i];
        bool flag = p > 1e-7f;
        unsigned long long mask = __ballot(flag);
        if (lane == 0) wsum[w] = __popcll(mask);
        __syncthreads();
        int base = rbase_s;
#pragma unroll
        for (int k = 0; k < 8; ++k) if (k < w) base += wsum[k];
        if (flag) {
            int pos = base + __popcll(mask & ((1ull << lane) - 1ull));
            idxs[pos] = s0 + i;
            ps[pos] = p;
        }
        __syncthreads();
        if (t == 0) {
            int sum = 0;
#pragma unroll
            for (int k = 0; k < 8; ++k) sum += wsum[k];
            rbase_s += sum;
        }
        __syncthreads();
    }
    const int cnt = rbase_s;

    float2 acc = {0.f, 0.f};
    for (int g = 0; g < cnt; g += 8) {
        __syncthreads();
        const int ng = cnt - g;
#pragma unroll
        for (int r = 0; r < 8; ++r) {
            float2 v = {0.f, 0.f};
            if (r < ng)
                v = ((const float2*)(x + ((size_t)b * S_ + idxs[g + r]) * D_))[t];
            ((float2*)xs[r])[t] = v;
        }
        __syncthreads();
        if (ng >= 5) {
            float2 a[8] = {};
#pragma unroll 2
            for (int dq = 0; dq < D_ / 4; ++dq) {
                const float* wrp = Wv + (size_t)dq * 4 * F_ + 2 * t;
                float2 wv0 = *(const float2*)(wrp         );
                float2 wv1 = *(const float2*)(wrp + F_    );
                float2 wv2 = *(const float2*)(wrp + 2 * F_);
                float2 wv3 = *(const float2*)(wrp + 3 * F_);
#pragma unroll
                for (int r = 0; r < 8; ++r) {
                    float4 xr = ((const float4*)xs[r])[dq];
                    fma2(a[r], xr.x, wv0); fma2(a[r], xr.y, wv1);
                    fma2(a[r], xr.z, wv2); fma2(a[r], xr.w, wv3);
                }
            }
#pragma unroll
            for (int r = 0; r < 8; ++r)
                if (g + r < cnt) {
                    float pw = ps[g + r];
                    acc.x += pw * tanhf(a[r].x);
                    acc.y += pw * tanhf(a[r].y);
                }
        } else {
            float2 a[4] = {};
#pragma unroll 2
            for (int dq = 0; dq < D_ / 4; ++dq) {
                const float* wrp = Wv + (size_t)dq * 4 * F_ + 2 * t;
                float2 wv0 = *(const float2*)(wrp         );
                float2 wv1 = *(const float2*)(wrp + F_    );
                float2 wv2 = *(const float2*)(wrp + 2 * F_);
                float2 wv3 = *(const float2*)(wrp + 3 * F_);
#pragma unroll
                for (int r = 0; r < 4; ++r) {
                    float4 xr = ((const float4*)xs[r])[dq];
                    fma2(a[r], xr.x, wv0); fma2(a[r], xr.y, wv1);
                    fma2(a[r], xr.z, wv2); fma2(a[r], xr.w, wv3);
                }
            }
#pragma unroll
            for (int r = 0; r < 4; ++r)
                if (g + r < cnt) {
                    float pw = ps[g + r];
                    acc.x += pw * tanhf(a[r].x);
                    acc.y += pw * tanhf(a[r].y);
                }
        }
    }
    ((float2*)(vpart + ((size_t)c * B_ + b) * F_))[t] = acc;
}

// ------------- kernel 4: reduce chunk partials -------------
__global__ void value_red(const float* __restrict__ vpart, float* __restrict__ out) {
    int i = blockIdx.x * 256 + threadIdx.x;
    float s = 0.f;
#pragma unroll
    for (int c = 0; c < NSV; ++c) s += vpart[(size_t)c * B_ * F_ + i];
    out[i] = s;
}

extern "C" void kernel_launch(void* const* d_in, const int* in_sizes, int n_in,
                              void* d_out, int out_size, void* d_ws, size_t ws_size,
                              hipStream_t stream) {
    const float* x  = (const float*)d_in[0];
    const float* Wk = (const float*)d_in[1];
    const float* Wq = (const float*)d_in[2];
    const float* Wv = (const float*)d_in[3];
    float* out = (float*)d_out;
    char* ws = (char*)d_ws;

    f16*   xh   = (f16*)ws;                                              // 128 MB
    f16*   wtf  = (f16*)(ws + (size_t)TOK * D_ * 2);                     // 4 MB frag-major W
    float* part = (float*)(ws + (size_t)TOK * D_ * 2 + 2 * (size_t)D_ * F_ * 2); // 4 MB

    cvt_x<<<TOK * D_ / 8 / 256, 256, 0, stream>>>(x, xh);
    cvt_w2<<<1024, 256, 0, stream>>>(Wk, Wq, wtf);
    score_gemm<<<NFB3 * (TOK / TB3), 256, 0, stream>>>(xh, wtf, part);
    softmax_k<<<B_, 256, 0, stream>>>(part, out);
    float* vpart = part;
    const float* p_in = out + (size_t)B_ * F_;
    value_k5<<<dim3(B_, NSV), 512, 0, stream>>>(x, Wv, p_in, vpart);
    value_red<<<B_ * F_ / 256, 256, 0, stream>>>(vpart, out);
}